// Round 11
// baseline (823.974 us; speedup 1.0000x reference)
//
#include <hip/hip_runtime.h>
#include <hip/hip_cooperative_groups.h>
#include <math.h>

namespace cg = cooperative_groups;

#define N_NODES 50000
#define N_EDGES 1000000
#define CCH     32
#define ROW     288           // 32 + 96 + 160
#define SCAN_BLOCKS 196       // ceil(50000/256)
#define REC_PAD 64            // float4 units of zero pad after rec (16 records)
#define BUILD_BLOCKS 1024     // cooperative grid: 4 blocks/CU, safely co-resident

// ---------------------------------------------------------------------------
// Shared edge-MLP + record write (used by coop build kernel and fallback pack)
//   rec[p] = [ h2*inv6 (6) | y0 (1) | y1 (3) | y2 (5) | sender-as-bits (1) ]
// ---------------------------------------------------------------------------
__device__ __forceinline__ void mlp_pack_one(
    const float* __restrict__ lenght, const float* __restrict__ ea9,
    const int* __restrict__ edge_index,
    const float* sw0, const float* sw1, const float* sw2,
    int e, int p, float4* __restrict__ rec)
{
    const float inv8 = 0.35355339059327373f;   // 1/sqrt(8)
    const float inv6 = 0.4082482904638631f;    // 1/sqrt(6)

    float len[8];
    const float4 l0 = ((const float4*)(lenght + (long long)e * 8))[0];
    const float4 l1 = ((const float4*)(lenght + (long long)e * 8))[1];
    len[0]=l0.x; len[1]=l0.y; len[2]=l0.z; len[3]=l0.w;
    len[4]=l1.x; len[5]=l1.y; len[6]=l1.z; len[7]=l1.w;

    float h0[6], h1[6], h2[6];
    #pragma unroll
    for (int j = 0; j < 6; ++j) {
        float a = 0.f;
        #pragma unroll
        for (int k = 0; k < 8; ++k) a += len[k] * sw0[k * 6 + j];
        a *= inv8;
        h0[j] = a / (1.f + __expf(-a));
    }
    #pragma unroll
    for (int j = 0; j < 6; ++j) {
        float a = 0.f;
        #pragma unroll
        for (int k = 0; k < 6; ++k) a += h0[k] * sw1[k * 6 + j];
        a *= inv6;
        h1[j] = a / (1.f + __expf(-a));
    }
    #pragma unroll
    for (int j = 0; j < 6; ++j) {
        float a = 0.f;
        #pragma unroll
        for (int k = 0; k < 6; ++k) a += h1[k] * sw2[k * 6 + j];
        a *= inv6;
        h2[j] = a * inv6 / (1.f + __expf(-a));   // fold final-layer 1/sqrt(6)
    }

    float y[9];
    #pragma unroll
    for (int i = 0; i < 9; ++i) y[i] = ea9[i];

    const int snd = edge_index[e];

    float4* rp = rec + (long long)p * 4;
    rp[0] = make_float4(h2[0], h2[1], h2[2], h2[3]);
    rp[1] = make_float4(h2[4], h2[5], y[0], y[1]);
    rp[2] = make_float4(y[2], y[3], y[4], y[5]);
    rp[3] = make_float4(y[6], y[7], y[8], __int_as_float(snd));
}

// ---------------------------------------------------------------------------
// COOP K1: the entire CSR build in ONE cooperative launch:
//   phase 0: zero deg + rec pad
//   phase 1: rank[e] = atomicAdd(&deg[recv], 1)
//   phase 2: hierarchical exclusive scan of deg -> offset
//   phase 3: edge MLP + pack records to CSR slots (slot = offset + rank)
// Replaces 2 memsets + 5 kernel launches (and their drain gaps).
// ---------------------------------------------------------------------------
__global__ __launch_bounds__(256) void build_kernel(
    const float* __restrict__ lenght,     // (E, 8)
    const float* __restrict__ edge_attr,  // (E, 9)
    const int*   __restrict__ edge_index, // (2, E)
    const float* __restrict__ fw0,        // (8, 6)
    const float* __restrict__ fw1,        // (6, 6)
    const float* __restrict__ fw2,        // (6, 6)
    int*         __restrict__ deg,        // (N)
    int*         __restrict__ rank,       // (E)
    int*         __restrict__ offset,     // (N)
    int*         __restrict__ lexcl,      // (N)
    int*         __restrict__ blocksum,   // (SCAN_BLOCKS)
    int*         __restrict__ blockpref,  // (SCAN_BLOCKS)
    float4*      __restrict__ rec)        // (E+pad, 4 x float4)
{
    cg::grid_group grid = cg::this_grid();

    __shared__ int   s_i[256];
    __shared__ float s_w[120];
    __shared__ float s_ea[256 * 9];

    const int t   = threadIdx.x;
    const int tid = blockIdx.x * 256 + t;
    const int NT  = gridDim.x * 256;

    // ---- phase 0: zero deg + rec pad ----
    for (int i = tid; i < N_NODES; i += NT) deg[i] = 0;
    {
        float4* recpad = rec + (size_t)N_EDGES * 4;
        if (tid < REC_PAD) recpad[tid] = make_float4(0.f, 0.f, 0.f, 0.f);
    }
    grid.sync();

    // ---- phase 1: histogram + per-edge rank ----
    for (int e = tid; e < N_EDGES; e += NT)
        rank[e] = atomicAdd(&deg[edge_index[N_EDGES + e]], 1);
    grid.sync();

    // ---- phase 2a: per-256-chunk scan (blocks 0..SCAN_BLOCKS-1) ----
    if (blockIdx.x < SCAN_BLOCKS) {
        const int gid = blockIdx.x * 256 + t;
        const int v = (gid < N_NODES) ? deg[gid] : 0;
        s_i[t] = v;
        __syncthreads();
        for (int ofs = 1; ofs < 256; ofs <<= 1) {
            int w = (t >= ofs) ? s_i[t - ofs] : 0;
            __syncthreads();
            s_i[t] += w;
            __syncthreads();
        }
        if (gid < N_NODES) lexcl[gid] = s_i[t] - v;
        if (t == 255) blocksum[blockIdx.x] = s_i[255];
    }
    grid.sync();

    // ---- phase 2b: block 0 scans the block sums ----
    if (blockIdx.x == 0) {
        const int v = (t < SCAN_BLOCKS) ? blocksum[t] : 0;
        s_i[t] = v;
        __syncthreads();
        for (int ofs = 1; ofs < 256; ofs <<= 1) {
            int w = (t >= ofs) ? s_i[t - ofs] : 0;
            __syncthreads();
            s_i[t] += w;
            __syncthreads();
        }
        if (t < SCAN_BLOCKS) blockpref[t] = s_i[t] - v;
    }
    grid.sync();

    // ---- phase 2c: offset = blockpref + lexcl ----
    for (int i = tid; i < N_NODES; i += NT)
        offset[i] = blockpref[i >> 8] + lexcl[i];
    grid.sync();

    // ---- phase 3: pack (tiled, edge_attr staged through LDS) ----
    for (int i = t; i < 120; i += 256)
        s_w[i] = (i < 48) ? fw0[i] : (i < 84) ? fw1[i - 48] : fw2[i - 84];
    const int NTILES = (N_EDGES + 255) / 256;
    for (int tile = blockIdx.x; tile < NTILES; tile += gridDim.x) {
        __syncthreads();                       // prev tile consumed / s_w ready
        const int base_dw = tile * (256 * 9);
        #pragma unroll
        for (int k = 0; k < 9; ++k) {
            const int i = k * 256 + t;
            const int g = base_dw + i;
            if (g < 9 * N_EDGES) s_ea[i] = edge_attr[g];
        }
        __syncthreads();
        const int e = tile * 256 + t;
        if (e < N_EDGES) {
            const int r = edge_index[N_EDGES + e];
            const int p = offset[r] + rank[e];
            mlp_pack_one(lenght, s_ea + t * 9, edge_index,
                         s_w, s_w + 48, s_w + 84, e, p, rec);
        }
    }
}

// ---------------------------------------------------------------------------
// FALLBACK path (only used if the cooperative launch is rejected): the
// round-8 proven kernel sequence.
// ---------------------------------------------------------------------------
__global__ __launch_bounds__(256) void rank_kernel(
    const int* __restrict__ edge_index, int* __restrict__ deg,
    int* __restrict__ rank)
{
    const int e = blockIdx.x * 256 + threadIdx.x;
    if (e >= N_EDGES) return;
    rank[e] = atomicAdd(&deg[edge_index[N_EDGES + e]], 1);
}

__global__ __launch_bounds__(256) void scan_local_kernel(
    const int* __restrict__ deg, int* __restrict__ lexcl, int* __restrict__ blocksum)
{
    __shared__ int s[256];
    const int t = threadIdx.x;
    const int gid = blockIdx.x * 256 + t;
    const int v = (gid < N_NODES) ? deg[gid] : 0;
    s[t] = v;
    __syncthreads();
    for (int ofs = 1; ofs < 256; ofs <<= 1) {
        int w = (t >= ofs) ? s[t - ofs] : 0;
        __syncthreads();
        s[t] += w;
        __syncthreads();
    }
    if (gid < N_NODES) lexcl[gid] = s[t] - v;
    if (t == 255) blocksum[blockIdx.x] = s[255];
}

__global__ __launch_bounds__(256) void scan_top_kernel(
    const int* __restrict__ blocksum, int* __restrict__ blockpref)
{
    __shared__ int s[256];
    const int t = threadIdx.x;
    const int v = (t < SCAN_BLOCKS) ? blocksum[t] : 0;
    s[t] = v;
    __syncthreads();
    for (int ofs = 1; ofs < 256; ofs <<= 1) {
        int w = (t >= ofs) ? s[t - ofs] : 0;
        __syncthreads();
        s[t] += w;
        __syncthreads();
    }
    if (t < SCAN_BLOCKS) blockpref[t] = s[t] - v;
}

__global__ __launch_bounds__(256) void scan_addback_kernel(
    const int* __restrict__ lexcl, const int* __restrict__ blockpref,
    int* __restrict__ offset)
{
    const int gid = blockIdx.x * 256 + threadIdx.x;
    if (gid >= N_NODES) return;
    offset[gid] = blockpref[blockIdx.x] + lexcl[gid];
}

__global__ __launch_bounds__(256) void pack_kernel(
    const float* __restrict__ lenght, const float* __restrict__ edge_attr,
    const int* __restrict__ edge_index,
    const float* __restrict__ fw0, const float* __restrict__ fw1,
    const float* __restrict__ fw2,
    const int* __restrict__ offset, const int* __restrict__ rank,
    float4* __restrict__ rec)
{
    __shared__ float s_w[120];
    __shared__ float s_ea[256 * 9];
    for (int i = threadIdx.x; i < 120; i += 256)
        s_w[i] = (i < 48) ? fw0[i] : (i < 84) ? fw1[i - 48] : fw2[i - 84];
    {
        const int base_dw = blockIdx.x * (256 * 9);
        #pragma unroll
        for (int k = 0; k < 9; ++k) {
            const int i = k * 256 + threadIdx.x;
            const int g = base_dw + i;
            if (g < 9 * N_EDGES) s_ea[i] = edge_attr[g];
        }
    }
    __syncthreads();

    const int e = blockIdx.x * 256 + threadIdx.x;
    if (e >= N_EDGES) return;
    const int r = edge_index[N_EDGES + e];
    const int p = offset[r] + rank[e];
    mlp_pack_one(lenght, s_ea + threadIdx.x * 9, edge_index,
                 s_w, s_w + 48, s_w + 84, e, p, rec);
}

// ---------------------------------------------------------------------------
// K4: gather — EXACT round-8 configuration (proven best: 118.7 us, VGPR 52).
// One 64-lane wave / node, 128-thread blocks (2 waves, 2 nodes), 25000
// blocks, no barriers, lw direct from global (L2-hot), A/B 2-edge ping-pong,
// zero-pad overshoot, LDS m-transpose epilogue, coalesced row store.
// Do NOT touch: launch_bounds minimum (r6: VGPR bloat), sched_barrier
// (r9: spills), batch-4 (r10: compiler re-serializes).
// ---------------------------------------------------------------------------
#define EDGE_ACC(Ra,Rb,Rc,Rd,xx) do {                                          \
    const float w0c_ = Ra.x*f3a[0] + Ra.y*f3a[1] + Ra.z*f3a[2]                 \
                     + Ra.w*f3a[3] + Rb.x*f3a[4] + Rb.y*f3a[5];                \
    const float w1c_ = Ra.x*f3b[0] + Ra.y*f3b[1] + Ra.z*f3b[2]                 \
                     + Ra.w*f3b[3] + Rb.x*f3b[4] + Rb.y*f3b[5];                \
    const float w2c_ = Ra.x*f3c[0] + Ra.y*f3c[1] + Ra.z*f3c[2]                 \
                     + Ra.w*f3c[3] + Rb.x*f3c[4] + Rb.y*f3c[5];                \
    acc[0] += (w0c_ * (xx)) * Rb.z;                                            \
    const float a1_ = w1c_ * (xx);                                             \
    acc[1] += a1_ * Rb.w; acc[2] += a1_ * Rc.x; acc[3] += a1_ * Rc.y;          \
    const float a2_ = w2c_ * (xx);                                             \
    acc[4] += a2_ * Rc.z; acc[5] += a2_ * Rc.w;                                \
    acc[6] += a2_ * Rd.x; acc[7] += a2_ * Rd.y; acc[8] += a2_ * Rd.z;          \
} while (0)

__global__ __launch_bounds__(128) void gather_kernel(
    const float4* __restrict__ rec,          // (E+pad, 4 x float4) CSR order
    const float*  __restrict__ node_features,// (N, 32)
    const int*    __restrict__ offset,       // (N)
    const int*    __restrict__ deg,          // (N)
    const float*  __restrict__ fw3,          // (6, 96)
    const float*  __restrict__ lw0,          // (32, 32)
    const float*  __restrict__ lw1,          // (32, 32)
    const float*  __restrict__ lw2,          // (32, 32)
    float*        __restrict__ out)          // (N, 288)
{
    __shared__ float s_m[2][384];            // per-wave: m-stage then row-stage

    const int wave = threadIdx.x >> 6;
    const int l    = threadIdx.x & 63;
    const int c    = l & 31;
    const int h    = l >> 5;
    const int node = blockIdx.x * 2 + wave;     // 25000 blocks exact

    float f3a[6], f3b[6], f3c[6];
    #pragma unroll
    for (int k = 0; k < 6; ++k) {
        f3a[k] = fw3[k * 96 + c];
        f3b[k] = fw3[k * 96 + 32 + c];
        f3c[k] = fw3[k * 96 + 64 + c];
    }

    int off = offset[node];
    int dg  = deg[node];
    off = __builtin_amdgcn_readfirstlane(off);   // wave-uniform -> SGPR
    dg  = __builtin_amdgcn_readfirstlane(dg);
    const int nph = (dg + 3) >> 2;               // phases (4 slots each)

    const float4* rb = rec + (size_t)off * 4;    // SGPR base

    float acc[9] = {0.f,0.f,0.f,0.f,0.f,0.f,0.f,0.f,0.f};

    if (nph > 0) {
        // slot pairs: A handles {jA, jA+1}, B handles {jB, jB+1}
        int jA = 2 * h;
        int jB = 2 * h + 4;

        // prologue: load both pairs, x for A pair
        float4 A0 = rb[4*jA+0], A1 = rb[4*jA+1], A2 = rb[4*jA+2], A3 = rb[4*jA+3];
        float4 A4 = rb[4*jA+4], A5 = rb[4*jA+5], A6 = rb[4*jA+6], A7 = rb[4*jA+7];
        float4 B0 = rb[4*jB+0], B1 = rb[4*jB+1], B2 = rb[4*jB+2], B3 = rb[4*jB+3];
        float4 B4 = rb[4*jB+4], B5 = rb[4*jB+5], B6 = rb[4*jB+6], B7 = rb[4*jB+7];
        float xAr0 = node_features[(size_t)__float_as_int(A3.w) * CCH + c];
        float xAr1 = node_features[(size_t)__float_as_int(A7.w) * CCH + c];
        bool  vA0 = (jA < dg), vA1 = (jA + 1 < dg);
        float xBr0 = 0.f, xBr1 = 0.f;
        bool  vB0 = false, vB1 = false;

        int p = 0;
        while (true) {
            // ---- phase A: compute pair A; issue x for B; prefetch next A ----
            {
                const float xA0 = vA0 ? xAr0 : 0.f;
                const float xA1 = vA1 ? xAr1 : 0.f;
                EDGE_ACC(A0, A1, A2, A3, xA0);
                EDGE_ACC(A4, A5, A6, A7, xA1);
                xBr0 = node_features[(size_t)__float_as_int(B3.w) * CCH + c];
                xBr1 = node_features[(size_t)__float_as_int(B7.w) * CCH + c];
                vB0 = (jB < dg); vB1 = (jB + 1 < dg);
                jA += 8;
                A0 = rb[4*jA+0]; A1 = rb[4*jA+1]; A2 = rb[4*jA+2]; A3 = rb[4*jA+3];
                A4 = rb[4*jA+4]; A5 = rb[4*jA+5]; A6 = rb[4*jA+6]; A7 = rb[4*jA+7];
                if (++p == nph) break;
            }
            // ---- phase B: compute pair B; issue x for A; prefetch next B ----
            {
                const float xB0 = vB0 ? xBr0 : 0.f;
                const float xB1 = vB1 ? xBr1 : 0.f;
                EDGE_ACC(B0, B1, B2, B3, xB0);
                EDGE_ACC(B4, B5, B6, B7, xB1);
                xAr0 = node_features[(size_t)__float_as_int(A3.w) * CCH + c];
                xAr1 = node_features[(size_t)__float_as_int(A7.w) * CCH + c];
                vA0 = (jA < dg); vA1 = (jA + 1 < dg);
                jB += 8;
                B0 = rb[4*jB+0]; B1 = rb[4*jB+1]; B2 = rb[4*jB+2]; B3 = rb[4*jB+3];
                B4 = rb[4*jB+4]; B5 = rb[4*jB+5]; B6 = rb[4*jB+6]; B7 = rb[4*jB+7];
                if (++p == nph) break;
            }
        }
    }

    // fold halves: lanes 0..31 hold msg[c][0..8]
    #pragma unroll
    for (int k = 0; k < 9; ++k) acc[k] += __shfl_down(acc[k], 32);

    // stage msg into LDS: s_m[wave][c*12 + k]  (48-B stride, b128-aligned)
    if (h == 0) {
        float4* mp = (float4*)&s_m[wave][c * 12];
        mp[0] = make_float4(acc[0], acc[1], acc[2], acc[3]);
        mp[1] = make_float4(acc[4], acc[5], acc[6], acc[7]);
        s_m[wave][c * 12 + 8] = acc[8];
    }
    asm volatile("s_waitcnt lgkmcnt(0)" ::: "memory");   // wave-internal fence

    // node linear: broadcast-read m from LDS, lw direct from global (L2-hot);
    // halves split the cc loop
    const int d = c;
    float o0 = 0.f;
    float o1[3] = {0.f, 0.f, 0.f};
    float o2[5] = {0.f, 0.f, 0.f, 0.f, 0.f};
    for (int cc = h * 16; cc < h * 16 + 16; ++cc) {
        const float4 ma = *(const float4*)&s_m[wave][cc * 12];
        const float4 mb = *(const float4*)&s_m[wave][cc * 12 + 4];
        const float  m8 = s_m[wave][cc * 12 + 8];
        o0 += ma.x * lw0[cc * 32 + d];
        const float w1 = lw1[cc * 32 + d];
        o1[0] += ma.y * w1; o1[1] += ma.z * w1; o1[2] += ma.w * w1;
        const float w2 = lw2[cc * 32 + d];
        o2[0] += mb.x * w2; o2[1] += mb.y * w2; o2[2] += mb.z * w2;
        o2[3] += mb.w * w2; o2[4] += m8   * w2;
    }

    o0 += __shfl_down(o0, 32);
    #pragma unroll
    for (int i = 0; i < 3; ++i) o1[i] += __shfl_down(o1[i], 32);
    #pragma unroll
    for (int i = 0; i < 5; ++i) o2[i] += __shfl_down(o2[i], 32);

    // stage the 288-float output row in LDS (reuse s_m), store coalesced
    if (h == 0) {
        const float inv32 = 0.17677669529663687f;  // 1/sqrt(32)
        float* rw = &s_m[wave][0];
        rw[d] = o0 * inv32;
        #pragma unroll
        for (int i = 0; i < 3; ++i) rw[32 + d * 3 + i] = o1[i] * inv32;
        #pragma unroll
        for (int i = 0; i < 5; ++i) rw[128 + d * 5 + i] = o2[i] * inv32;
    }
    asm volatile("s_waitcnt lgkmcnt(0)" ::: "memory");

    const float4* rowp = (const float4*)&s_m[wave][0];
    float4* op4 = (float4*)(out + (size_t)node * ROW);
    op4[l] = rowp[l];
    if (l < 8) op4[64 + l] = rowp[64 + l];
}

extern "C" void kernel_launch(void* const* d_in, const int* in_sizes, int n_in,
                              void* d_out, int out_size, void* d_ws, size_t ws_size,
                              hipStream_t stream)
{
    const float* lenght = (const float*)d_in[0];
    const float* nf     = (const float*)d_in[1];
    const float* ea     = (const float*)d_in[2];
    const int*   ei     = (const int*)d_in[3];
    const float* fw0    = (const float*)d_in[4];
    const float* fw1    = (const float*)d_in[5];
    const float* fw2    = (const float*)d_in[6];
    const float* fw3    = (const float*)d_in[7];
    const float* lw0    = (const float*)d_in[8];
    const float* lw1    = (const float*)d_in[9];
    const float* lw2    = (const float*)d_in[10];
    float* out = (float*)d_out;

    // workspace layout
    char* ws = (char*)d_ws;
    float4* rec    = (float4*)ws; ws += ((size_t)N_EDGES * 4 + REC_PAD) * sizeof(float4);
    int* rank      = (int*)ws;    ws += (size_t)N_EDGES * sizeof(int);
    int* deg       = (int*)ws;    ws += (size_t)N_NODES * sizeof(int);
    int* offset    = (int*)ws;    ws += (size_t)N_NODES * sizeof(int);
    int* lexcl     = (int*)ws;    ws += (size_t)N_NODES * sizeof(int);
    int* blocksum  = (int*)ws;    ws += (size_t)SCAN_BLOCKS * sizeof(int);
    int* blockpref = (int*)ws;    ws += (size_t)SCAN_BLOCKS * sizeof(int);
    float4* recpad = rec + (size_t)N_EDGES * 4;

    // --- one cooperative launch for the whole CSR build ---
    void* kargs[] = {
        (void*)&lenght, (void*)&ea, (void*)&ei,
        (void*)&fw0, (void*)&fw1, (void*)&fw2,
        (void*)&deg, (void*)&rank, (void*)&offset,
        (void*)&lexcl, (void*)&blocksum, (void*)&blockpref, (void*)&rec
    };
    hipError_t rc = hipLaunchCooperativeKernel(
        (void*)build_kernel, dim3(BUILD_BLOCKS), dim3(256), kargs, 0, stream);

    if (rc != hipSuccess) {
        // fallback: proven round-8 sequence
        hipMemsetAsync(deg, 0, (size_t)N_NODES * sizeof(int), stream);
        hipMemsetAsync(recpad, 0, (size_t)REC_PAD * sizeof(float4), stream);
        const int EB = (N_EDGES + 255) / 256;
        rank_kernel        <<<EB, 256, 0, stream>>>(ei, deg, rank);
        scan_local_kernel  <<<SCAN_BLOCKS, 256, 0, stream>>>(deg, lexcl, blocksum);
        scan_top_kernel    <<<1, 256, 0, stream>>>(blocksum, blockpref);
        scan_addback_kernel<<<SCAN_BLOCKS, 256, 0, stream>>>(lexcl, blockpref, offset);
        pack_kernel        <<<EB, 256, 0, stream>>>(lenght, ea, ei, fw0, fw1, fw2,
                                                    offset, rank, rec);
    }

    gather_kernel<<<N_NODES / 2, 128, 0, stream>>>(
        rec, nf, offset, deg, fw3, lw0, lw1, lw2, out);
}